// Round 9
// baseline (16790.804 us; speedup 1.0000x reference)
//
#include <hip/hip_runtime.h>
#include <hip/hip_bf16.h>

#define TOK 8192
#define OUTD 768
#define KD 32768

#define BM 256                     // 2x bigger m-tile: halves W re-reads
#define BN 768                     // full output width: X read exactly once
#define BK 32
#define SPLITK 8
#define KCHUNK (KD / SPLITK)       // 4096
#define NKT (KCHUNK / BK)          // 128 steps
#define NHT_TOT (KD / BK)          // 1024 32-k tiles of W
#define THREADS 1024               // 16 waves: 4M x 4N
#define HTILE (BN * BK * 2)        // 49152 B (48KB swizzled W tile image)
#define ATILE (BM * BK * 2)        // 16384 B

typedef __attribute__((ext_vector_type(4))) float f32x4;
typedef __attribute__((ext_vector_type(16))) float f32x16;
typedef __attribute__((ext_vector_type(8))) short bf16x8;
typedef __attribute__((ext_vector_type(4))) unsigned int u32x4;

__device__ __forceinline__ unsigned pack2(float lo, float hi) {
    __hip_bfloat162 h = __float22bfloat162_rn(make_float2(lo, hi));
    unsigned u;
    __builtin_memcpy(&u, &h, 4);
    return u;
}

__device__ __forceinline__ u32x4 cvt_chunk(f32x4 a, f32x4 b) {
    u32x4 r;
    r[0] = pack2(a[0], a[1]);
    r[1] = pack2(a[2], a[3]);
    r[2] = pack2(b[0], b[1]);
    r[3] = pack2(b[2], b[3]);
    return r;
}

// ---------------------------------------------------------------------------
// Kernel 0: negc[o] = -dot(W[o,:], b_pre)   (rank-1 bias correction)
// ---------------------------------------------------------------------------
__global__ void colbias_kernel(const float* __restrict__ W,
                               const float* __restrict__ bp,
                               float* __restrict__ negc) {
    int o = blockIdx.x;
    int tid = threadIdx.x;  // 256
    const float* wr = W + (long)o * KD;
    float s = 0.f;
    for (int i = tid * 4; i < KD; i += 256 * 4) {
        f32x4 w = *(const f32x4*)(wr + i);
        f32x4 b = *(const f32x4*)(bp + i);
        s += w[0] * b[0] + w[1] * b[1] + w[2] * b[2] + w[3] * b[3];
    }
    #pragma unroll
    for (int off = 32; off > 0; off >>= 1) s += __shfl_down(s, off);
    __shared__ float red[4];
    if ((tid & 63) == 0) red[tid >> 6] = s;
    __syncthreads();
    if (tid == 0) negc[o] = -(red[0] + red[1] + red[2] + red[3]);
}

// ---------------------------------------------------------------------------
// Kernel 1: out[n][o] = negc[o]   (init; zero-base for split-K atomics)
// ---------------------------------------------------------------------------
__global__ void init_kernel(const float* __restrict__ negc,
                            float* __restrict__ out) {
    long idx = ((long)blockIdx.x * blockDim.x + threadIdx.x) * 4;
    int col = (int)(idx % OUTD);
    f32x4 v = *(const f32x4*)(negc + col);
    *(f32x4*)(out + idx) = v;
}

// ---------------------------------------------------------------------------
// Kernel 1.5: cast W f32 -> bf16 into ws as 1024 swizzled 48KB tile images.
// Per tile: byte = col*64 + ((octet ^ ((col>>1)&3))<<4) + (k&7)*2.
// ---------------------------------------------------------------------------
__global__ void cast_w_kernel(const float* __restrict__ W,
                              char* __restrict__ wsW) {
    int kth = blockIdx.x;    // 0..1023, 32-k tile index
    int tid = threadIdx.x;   // 512
    int q = tid & 3;         // k-octet
    int c0 = tid >> 2;       // 0..127
    #pragma unroll
    for (int i = 0; i < 6; ++i) {
        int c = c0 + i * 128;  // 0..767
        const float* src = W + (long)c * KD + kth * 32 + q * 8;
        f32x4 a = ((const f32x4*)src)[0];
        f32x4 b = ((const f32x4*)src)[1];
        char* dst = wsW + (long)kth * HTILE + c * 64 +
                    ((q ^ ((c >> 1) & 3)) << 4);
        *(u32x4*)dst = cvt_chunk(a, b);
    }
}

// ---------------------------------------------------------------------------
// Kernel 2: split-K bf16 GEMM, 256 rows x FULL 768 cols per block,
// 1024 threads (16 waves, 4M x 4N), double-buffered at BK=32, round-6
// schedule (ISSUEB+LOADA at top, one __syncthreads per step).
//   A (x f32): reg-prefetch -> cvt -> swizzled ds_write (other buffer).
//   B (W bf16): global_load_lds DMA of pre-swizzled ws image (other buffer).
// ---------------------------------------------------------------------------
__global__ __launch_bounds__(THREADS, 1) void decoder_gemm(
    const float* __restrict__ X, const char* __restrict__ Wb16,
    float* __restrict__ Out) {
    __shared__ char lds[2 * ATILE + 2 * HTILE];  // A0 A1 B0 B1 = 128KB
    char* ldsA = lds;
    char* ldsB = lds + 2 * ATILE;

    const int bid = blockIdx.x;     // 256 blocks = 1/CU; ks = bid&7 -> one
    const int ks = bid & (SPLITK - 1);  //   6MB W-chunk per XCD
    const int mt = bid >> 3;
    const int row0 = mt * BM;

    const int tid = threadIdx.x;
    const int lane = tid & 63;
    const int wid = tid >> 6;  // 0..15
    const int wm = wid >> 2;   // 0..3 -> 64-row quarter
    const int wn = wid & 3;    // 0..3 -> 192-col quarter
    const int l31 = lane & 31;
    const int hi = lane >> 5;

    const float* Xb = X + (long)row0 * KD + (long)ks * KCHUNK;
    const char* Wt0 = Wb16 + (long)ks * NKT * HTILE;

    // A staging: 1024 threads = 256 rows x 4 k-octets, 8 f32 each
    const int ar = tid >> 2;   // 0..255
    const int aq = tid & 3;
    f32x4 xr[2];

    auto LOADA = [&](int kt) {
        const f32x4* p = (const f32x4*)(Xb + (long)ar * KD + kt * 32 + aq * 8);
        xr[0] = p[0];
        xr[1] = p[1];
    };

    const int asoff = ar * 64 + ((aq ^ ((ar >> 1) & 3)) << 4);

    auto STOREA = [&](int buf) {
        *(u32x4*)(ldsA + buf * ATILE + asoff) = cvt_chunk(xr[0], xr[1]);
    };

    auto ISSUEB = [&](int kt, int buf) {
        const char* src = Wt0 + (long)kt * HTILE + tid * 16;
        char* dst = ldsB + buf * HTILE + tid * 16;
        #pragma unroll
        for (int j = 0; j < 3; ++j)
            __builtin_amdgcn_global_load_lds(
                (const __attribute__((address_space(1))) void*)(src + j * 16384),
                (__attribute__((address_space(3))) void*)(dst + j * 16384),
                16, 0, 0);
    };

    // fragment offsets: octet o = kk*2 + hi; slot = o ^ ((row>>1)&3);
    // byte = row*64 + slot*16; kk flips bit1 -> XOR (kk<<5)
    int aoff[2], boff[6];
    #pragma unroll
    for (int m = 0; m < 2; ++m) {
        int row = wm * 64 + m * 32 + l31;
        aoff[m] = row * 64 + ((hi ^ ((row >> 1) & 3)) << 4);
    }
    #pragma unroll
    for (int n = 0; n < 6; ++n) {
        int col = wn * 192 + n * 32 + l31;
        boff[n] = col * 64 + ((hi ^ ((col >> 1) & 3)) << 4);
    }

    f32x16 acc[2][6];
    #pragma unroll
    for (int m = 0; m < 2; ++m)
        #pragma unroll
        for (int n = 0; n < 6; ++n)
            #pragma unroll
            for (int r = 0; r < 16; ++r) acc[m][n][r] = 0.f;

    auto COMPUTE = [&](int cur) {
        const char* As = ldsA + cur * ATILE;
        const char* Bs = ldsB + cur * HTILE;
        #pragma unroll
        for (int kk = 0; kk < 2; ++kk) {
            bf16x8 afr[2], bfr[6];
            #pragma unroll
            for (int m = 0; m < 2; ++m)
                afr[m] = *(const bf16x8*)(As + (aoff[m] ^ (kk << 5)));
            #pragma unroll
            for (int n = 0; n < 6; ++n)
                bfr[n] = *(const bf16x8*)(Bs + (boff[n] ^ (kk << 5)));
            __builtin_amdgcn_s_setprio(1);
            #pragma unroll
            for (int m = 0; m < 2; ++m)
                #pragma unroll
                for (int n = 0; n < 6; ++n)
                    acc[m][n] = __builtin_amdgcn_mfma_f32_32x32x16_bf16(
                        afr[m], bfr[n], acc[m][n], 0, 0, 0);
            __builtin_amdgcn_s_setprio(0);
        }
    };

    // prologue: tile 0 into buffer 0
    ISSUEB(0, 0);
    LOADA(0);
    STOREA(0);          // counted wait on own loads (B DMA older -> done too)
    __syncthreads();

    for (int kt = 0; kt < NKT; ++kt) {
        const int cur = kt & 1;
        const bool more = (kt + 1 < NKT);
        if (more) {
            ISSUEB(kt + 1, cur ^ 1);  // DMA streams under the whole compute
            LOADA(kt + 1);
        }
        COMPUTE(cur);
        if (more) STOREA(cur ^ 1);
        __syncthreads();            // publish buffer cur^1 for next step
    }

    // epilogue: 32x32 C/D layout: col=lane&31, row=(r&3)+8*(r>>2)+4*(lane>>5)
    #pragma unroll
    for (int m = 0; m < 2; ++m) {
        int rowb = row0 + wm * 64 + m * 32 + 4 * hi;
        #pragma unroll
        for (int n = 0; n < 6; ++n) {
            int col = wn * 192 + n * 32 + l31;
            #pragma unroll
            for (int r = 0; r < 16; ++r) {
                int row = rowb + (r & 3) + 8 * (r >> 2);
                atomicAdd(&Out[(long)row * OUTD + col], acc[m][n][r]);
            }
        }
    }
}

// ---------------------------------------------------------------------------
extern "C" void kernel_launch(void* const* d_in, const int* in_sizes, int n_in,
                              void* d_out, int out_size, void* d_ws,
                              size_t ws_size, hipStream_t stream) {
    const float* x = (const float*)d_in[0];
    const float* W = (const float*)d_in[1];
    const float* bp = (const float*)d_in[2];
    float* out = (float*)d_out;
    float* negc = (float*)d_ws;
    char* wsW = (char*)d_ws + 4096;
    // ws need: 4096 + 1024*49152 = 50.3 MB (proven available rounds 3/5-8)

    hipLaunchKernelGGL(colbias_kernel, dim3(OUTD), dim3(256), 0, stream, W, bp,
                       negc);
    hipLaunchKernelGGL(init_kernel, dim3((TOK * OUTD) / (256 * 4)), dim3(256),
                       0, stream, negc, out);
    hipLaunchKernelGGL(cast_w_kernel, dim3(NHT_TOT), dim3(512), 0, stream, W,
                       wsW);
    hipLaunchKernelGGL(decoder_gemm, dim3((TOK / BM) * SPLITK), dim3(THREADS),
                       0, stream, x, wsW, out);
}

// Round 10
// 801.663 us; speedup vs baseline: 20.9450x; 20.9450x over previous
//
#include <hip/hip_runtime.h>
#include <hip/hip_bf16.h>

#define TOK 8192
#define OUTD 768
#define KD 32768

#define BM 128
#define BN 768                     // full output width: X read exactly once
#define BK 32
#define SPLITK 8
#define KCHUNK (KD / SPLITK)       // 4096
#define NKT (KCHUNK / BK)          // 128 steps
#define NHT_TOT (KD / BK)          // 1024 32-k tiles of W
#define THREADS 512
#define HTILE (BN * BK * 2)        // 49152 B (48KB W tile image, plane-major)
#define ATILE (BM * BK * 2)        // 8192 B

typedef __attribute__((ext_vector_type(4))) float f32x4;
typedef __attribute__((ext_vector_type(16))) float f32x16;
typedef __attribute__((ext_vector_type(8))) short bf16x8;
typedef __attribute__((ext_vector_type(4))) unsigned int u32x4;

__device__ __forceinline__ unsigned pack2(float lo, float hi) {
    __hip_bfloat162 h = __float22bfloat162_rn(make_float2(lo, hi));
    unsigned u;
    __builtin_memcpy(&u, &h, 4);
    return u;
}

__device__ __forceinline__ u32x4 cvt_chunk(f32x4 a, f32x4 b) {
    u32x4 r;
    r[0] = pack2(a[0], a[1]);
    r[1] = pack2(a[2], a[3]);
    r[2] = pack2(b[0], b[1]);
    r[3] = pack2(b[2], b[3]);
    return r;
}

// ---------------------------------------------------------------------------
// Kernel 0: negc[o] = -dot(W[o,:], b_pre)   (rank-1 bias correction)
// ---------------------------------------------------------------------------
__global__ void colbias_kernel(const float* __restrict__ W,
                               const float* __restrict__ bp,
                               float* __restrict__ negc) {
    int o = blockIdx.x;
    int tid = threadIdx.x;  // 256
    const float* wr = W + (long)o * KD;
    float s = 0.f;
    for (int i = tid * 4; i < KD; i += 256 * 4) {
        f32x4 w = *(const f32x4*)(wr + i);
        f32x4 b = *(const f32x4*)(bp + i);
        s += w[0] * b[0] + w[1] * b[1] + w[2] * b[2] + w[3] * b[3];
    }
    #pragma unroll
    for (int off = 32; off > 0; off >>= 1) s += __shfl_down(s, off);
    __shared__ float red[4];
    if ((tid & 63) == 0) red[tid >> 6] = s;
    __syncthreads();
    if (tid == 0) negc[o] = -(red[0] + red[1] + red[2] + red[3]);
}

// ---------------------------------------------------------------------------
// Kernel 1: out[n][o] = negc[o]   (init; zero-base for split-K atomics)
// ---------------------------------------------------------------------------
__global__ void init_kernel(const float* __restrict__ negc,
                            float* __restrict__ out) {
    long idx = ((long)blockIdx.x * blockDim.x + threadIdx.x) * 4;
    int col = (int)(idx % OUTD);
    f32x4 v = *(const f32x4*)(negc + col);
    *(f32x4*)(out + idx) = v;
}

// ---------------------------------------------------------------------------
// Kernel 1.5: cast W f32 -> bf16 into ws as 1024 48KB tile images,
// PLANE-MAJOR: 16B unit p = octet*768 + col, byte = p*16.
// Fragment reads (32 lanes, col = c0 + lane&31, fixed octet) then have
// p % 32 == lane&31 -> canonical linear bank pattern, conflict-free.
// ---------------------------------------------------------------------------
__global__ void cast_w_kernel(const float* __restrict__ W,
                              char* __restrict__ wsW) {
    int kth = blockIdx.x;    // 0..1023, 32-k tile index
    int tid = threadIdx.x;   // 512
    int q = tid & 3;         // k-octet
    int c0 = tid >> 2;       // 0..127
    #pragma unroll
    for (int i = 0; i < 6; ++i) {
        int c = c0 + i * 128;  // 0..767
        const float* src = W + (long)c * KD + kth * 32 + q * 8;
        f32x4 a = ((const f32x4*)src)[0];
        f32x4 b = ((const f32x4*)src)[1];
        char* dst = wsW + (long)kth * HTILE + ((q * 768 + c) << 4);
        *(u32x4*)dst = cvt_chunk(a, b);
    }
}

// ---------------------------------------------------------------------------
// Kernel 2: split-K bf16 GEMM, 128 rows x FULL 768 cols per block, 512 thr
// (8 waves, 2M x 4N), double-buffered at BK=32, round-6 schedule.
//   ks = bid & 7: with round-robin bid->XCD dispatch, each XCD works ONE
//   6MB W-chunk for the whole kernel -> W streams through its private L2.
//   A (x f32): reg-prefetch -> cvt -> plane-major ds_write (other buffer).
//   B (W bf16): global_load_lds DMA of plane-major ws image (other buffer).
// ---------------------------------------------------------------------------
__global__ __launch_bounds__(THREADS, 2) void decoder_gemm(
    const float* __restrict__ X, const char* __restrict__ Wb16,
    float* __restrict__ Out) {
    __shared__ char lds[2 * ATILE + 2 * HTILE];  // A0 A1 B0 B1 = 112KB
    char* ldsA = lds;
    char* ldsB = lds + 2 * ATILE;

    const int bid = blockIdx.x;         // 512 blocks = 2 rounds of 256
    const int ks = bid & (SPLITK - 1);  // == XCD id under %8 round-robin
    const int mt = bid >> 3;            // 0..63
    const int row0 = mt * BM;

    const int tid = threadIdx.x;
    const int lane = tid & 63;
    const int wid = tid >> 6;  // 0..7
    const int wm = wid >> 2;   // 0..1 -> 64-row half
    const int wn = wid & 3;    // 0..3 -> 192-col quarter
    const int l31 = lane & 31;
    const int hi = lane >> 5;

    const float* Xb = X + (long)row0 * KD + (long)ks * KCHUNK;
    const char* Wt0 = Wb16 + (long)ks * NKT * HTILE;

    // A staging: 512 threads = 128 rows x 4 k-octets, 8 f32 each
    const int ar = tid >> 2;   // 0..127
    const int aq = tid & 3;
    f32x4 xr[2];

    auto LOADA = [&](int kt) {
        const f32x4* p = (const f32x4*)(Xb + (long)ar * KD + kt * 32 + aq * 8);
        xr[0] = p[0];
        xr[1] = p[1];
    };

    // A image plane-major: byte = (octet*128 + row)*16
    const int asoff = (aq * 128 + ar) << 4;

    auto STOREA = [&](int buf) {
        *(u32x4*)(ldsA + buf * ATILE + asoff) = cvt_chunk(xr[0], xr[1]);
    };

    auto ISSUEB = [&](int kt, int buf) {
        const char* src = Wt0 + (long)kt * HTILE + tid * 16;
        char* dst = ldsB + buf * HTILE + tid * 16;
        #pragma unroll
        for (int j = 0; j < 6; ++j)
            __builtin_amdgcn_global_load_lds(
                (const __attribute__((address_space(1))) void*)(src + j * 8192),
                (__attribute__((address_space(3))) void*)(dst + j * 8192),
                16, 0, 0);
    };

    // fragment byte offsets (kk=0; kk adds a fixed plane-pair stride)
    //   A: (o*128 + row)*16, o = 2*kk + hi   -> +4096 per kk
    //   B: (o*768 + col)*16                  -> +24576 per kk
    int aoff[2], boff[6];
    #pragma unroll
    for (int m = 0; m < 2; ++m) {
        int row = wm * 64 + m * 32 + l31;
        aoff[m] = (hi * 128 + row) << 4;
    }
    #pragma unroll
    for (int n = 0; n < 6; ++n) {
        int col = wn * 192 + n * 32 + l31;
        boff[n] = (hi * 768 + col) << 4;
    }

    f32x16 acc[2][6];
    #pragma unroll
    for (int m = 0; m < 2; ++m)
        #pragma unroll
        for (int n = 0; n < 6; ++n)
            #pragma unroll
            for (int r = 0; r < 16; ++r) acc[m][n][r] = 0.f;

    auto COMPUTE = [&](int cur) {
        const char* As = ldsA + cur * ATILE;
        const char* Bs = ldsB + cur * HTILE;
        #pragma unroll
        for (int kk = 0; kk < 2; ++kk) {
            bf16x8 afr[2], bfr[6];
            #pragma unroll
            for (int m = 0; m < 2; ++m)
                afr[m] = *(const bf16x8*)(As + aoff[m] + kk * 4096);
            #pragma unroll
            for (int n = 0; n < 6; ++n)
                bfr[n] = *(const bf16x8*)(Bs + boff[n] + kk * 24576);
            __builtin_amdgcn_s_setprio(1);
            #pragma unroll
            for (int m = 0; m < 2; ++m)
                #pragma unroll
                for (int n = 0; n < 6; ++n)
                    acc[m][n] = __builtin_amdgcn_mfma_f32_32x32x16_bf16(
                        afr[m], bfr[n], acc[m][n], 0, 0, 0);
            __builtin_amdgcn_s_setprio(0);
        }
    };

    // prologue: tile 0 into buffer 0
    ISSUEB(0, 0);
    LOADA(0);
    STOREA(0);          // counted wait on own loads (B DMA older -> done too)
    __syncthreads();

    for (int kt = 0; kt < NKT; ++kt) {
        const int cur = kt & 1;
        const bool more = (kt + 1 < NKT);
        if (more) {
            ISSUEB(kt + 1, cur ^ 1);  // DMA streams under the whole compute
            LOADA(kt + 1);
        }
        COMPUTE(cur);
        if (more) STOREA(cur ^ 1);
        __syncthreads();            // publish buffer cur^1 for next step
    }

    // epilogue: 32x32 C/D layout: col=lane&31, row=(r&3)+8*(r>>2)+4*(lane>>5)
    #pragma unroll
    for (int m = 0; m < 2; ++m) {
        int rowb = row0 + wm * 64 + m * 32 + 4 * hi;
        #pragma unroll
        for (int n = 0; n < 6; ++n) {
            int col = wn * 192 + n * 32 + l31;
            #pragma unroll
            for (int r = 0; r < 16; ++r) {
                int row = rowb + (r & 3) + 8 * (r >> 2);
                atomicAdd(&Out[(long)row * OUTD + col], acc[m][n][r]);
            }
        }
    }
}

// ---------------------------------------------------------------------------
extern "C" void kernel_launch(void* const* d_in, const int* in_sizes, int n_in,
                              void* d_out, int out_size, void* d_ws,
                              size_t ws_size, hipStream_t stream) {
    const float* x = (const float*)d_in[0];
    const float* W = (const float*)d_in[1];
    const float* bp = (const float*)d_in[2];
    float* out = (float*)d_out;
    float* negc = (float*)d_ws;
    char* wsW = (char*)d_ws + 4096;
    // ws need: 4096 + 1024*49152 = 50.3 MB (proven available rounds 3/5-9)

    hipLaunchKernelGGL(colbias_kernel, dim3(OUTD), dim3(256), 0, stream, W, bp,
                       negc);
    hipLaunchKernelGGL(init_kernel, dim3((TOK * OUTD) / (256 * 4)), dim3(256),
                       0, stream, negc, out);
    hipLaunchKernelGGL(cast_w_kernel, dim3(NHT_TOT), dim3(512), 0, stream, W,
                       wsW);
    hipLaunchKernelGGL(decoder_gemm, dim3((TOK / BM) * SPLITK), dim3(THREADS),
                       0, stream, x, wsW, out);
}

// Round 11
// 574.393 us; speedup vs baseline: 29.2322x; 1.3957x over previous
//
#include <hip/hip_runtime.h>
#include <hip/hip_bf16.h>

#define TOK 8192
#define OUTD 768
#define KD 32768

#define BM 128
#define BN 768                     // full output width: X read exactly once
#define BK 32                      // small K-step so full-width tile can dbuf
#define SPLITK 4
#define KCHUNK (KD / SPLITK)       // 8192
#define NKT (KCHUNK / BK)          // 256 steps
#define NHT_TOT (KD / BK)          // 1024 32-k tiles of W
#define THREADS 512
#define HTILE (BN * BK * 2)        // 49152 B (48KB swizzled W tile image)
#define ATILE (BM * BK * 2)        // 8192 B

// ws layout: [0,3072)=negc | 4096 + 48MB W image | +50335744 partials 100MB
#define WSOFF_W 4096
#define WSOFF_P (WSOFF_W + (long)NHT_TOT * HTILE)   // 50,335,744
#define PSTRIDE ((long)TOK * OUTD)                  // per-ks partial plane

typedef __attribute__((ext_vector_type(4))) float f32x4;
typedef __attribute__((ext_vector_type(16))) float f32x16;
typedef __attribute__((ext_vector_type(8))) short bf16x8;
typedef __attribute__((ext_vector_type(4))) unsigned int u32x4;

__device__ __forceinline__ unsigned pack2(float lo, float hi) {
    __hip_bfloat162 h = __float22bfloat162_rn(make_float2(lo, hi));
    unsigned u;
    __builtin_memcpy(&u, &h, 4);
    return u;
}

__device__ __forceinline__ u32x4 cvt_chunk(f32x4 a, f32x4 b) {
    u32x4 r;
    r[0] = pack2(a[0], a[1]);
    r[1] = pack2(a[2], a[3]);
    r[2] = pack2(b[0], b[1]);
    r[3] = pack2(b[2], b[3]);
    return r;
}

// ---------------------------------------------------------------------------
// Kernel 0: negc[o] = -dot(W[o,:], b_pre)   (rank-1 bias correction)
// ---------------------------------------------------------------------------
__global__ void colbias_kernel(const float* __restrict__ W,
                               const float* __restrict__ bp,
                               float* __restrict__ negc) {
    int o = blockIdx.x;
    int tid = threadIdx.x;  // 256
    const float* wr = W + (long)o * KD;
    float s = 0.f;
    for (int i = tid * 4; i < KD; i += 256 * 4) {
        f32x4 w = *(const f32x4*)(wr + i);
        f32x4 b = *(const f32x4*)(bp + i);
        s += w[0] * b[0] + w[1] * b[1] + w[2] * b[2] + w[3] * b[3];
    }
    #pragma unroll
    for (int off = 32; off > 0; off >>= 1) s += __shfl_down(s, off);
    __shared__ float red[4];
    if ((tid & 63) == 0) red[tid >> 6] = s;
    __syncthreads();
    if (tid == 0) negc[o] = -(red[0] + red[1] + red[2] + red[3]);
}

// ---------------------------------------------------------------------------
// Kernel 1: cast W f32 -> bf16 into ws as 1024 swizzled 48KB tile images
// (EXACT r6 layout: byte = col*64 + ((octet ^ (col&3))<<4); coalesced 64B
// writes per 4-lane group).
// ---------------------------------------------------------------------------
__global__ void cast_w_kernel(const float* __restrict__ W,
                              char* __restrict__ wsW) {
    int kth = blockIdx.x;    // 0..1023, 32-k tile index
    int tid = threadIdx.x;   // 512
    int q = tid & 3;         // k-octet
    int c0 = tid >> 2;       // 0..127
    #pragma unroll
    for (int i = 0; i < 6; ++i) {
        int c = c0 + i * 128;  // 0..767
        const float* src = W + (long)c * KD + kth * 32 + q * 8;
        f32x4 a = ((const f32x4*)src)[0];
        f32x4 b = ((const f32x4*)src)[1];
        char* dst = wsW + (long)kth * HTILE + c * 64 + ((q ^ (c & 3)) << 4);
        *(u32x4*)dst = cvt_chunk(a, b);
    }
}

// ---------------------------------------------------------------------------
// Kernel 2: split-K bf16 GEMM — K-loop BYTE-EXACT to round 6 (596us best).
// Only the epilogue differs: plain coalesced stores of the split-K partial
// into wsP[ks] instead of atomicAdd into Out.
// ---------------------------------------------------------------------------
__global__ __launch_bounds__(THREADS, 2) void decoder_gemm(
    const float* __restrict__ X, const char* __restrict__ Wb16,
    float* __restrict__ P) {
    __shared__ char lds[2 * ATILE + 2 * HTILE];  // A0 A1 B0 B1 = 112KB
    char* ldsA = lds;
    char* ldsB = lds + 2 * ATILE;

    const int bid = blockIdx.x;     // 256 blocks; ks fastest
    const int ks = bid & (SPLITK - 1);
    const int mt = bid >> 2;
    const int row0 = mt * BM;

    const int tid = threadIdx.x;
    const int lane = tid & 63;
    const int wid = tid >> 6;
    const int wm = wid >> 2;   // 0..1 -> 64-row half
    const int wn = wid & 3;    // 0..3 -> 192-col quarter
    const int l31 = lane & 31;
    const int hi = lane >> 5;

    const float* Xb = X + (long)row0 * KD + (long)ks * KCHUNK;
    const char* Wt0 = Wb16 + (long)ks * NKT * HTILE;

    // A staging: thread -> (row ar, k-octet aq); 512 = 128 rows x 4 octets
    const int ar = tid >> 2;   // 0..127
    const int aq = tid & 3;
    f32x4 xr[2];

    auto LOADA = [&](int kt) {
        const f32x4* p = (const f32x4*)(Xb + (long)ar * KD + kt * 32 + aq * 8);
        xr[0] = p[0];
        xr[1] = p[1];
    };

    const int asoff = ar * 64 + ((aq ^ (ar & 3)) << 4);

    auto STOREA = [&](int buf) {
        *(u32x4*)(ldsA + buf * ATILE + asoff) = cvt_chunk(xr[0], xr[1]);
    };

    auto ISSUEB = [&](int kt, int buf) {
        const char* src = Wt0 + (long)kt * HTILE + tid * 16;
        char* dst = ldsB + buf * HTILE + tid * 16;
        #pragma unroll
        for (int j = 0; j < 6; ++j)
            __builtin_amdgcn_global_load_lds(
                (const __attribute__((address_space(1))) void*)(src + j * 8192),
                (__attribute__((address_space(3))) void*)(dst + j * 8192),
                16, 0, 0);
    };

    // fragment offsets: octet o = kk*2 + hi; slot = o ^ (row&3);
    // byte = row*64 + slot*16; kk flips bit1 -> XOR (kk<<5)
    int aoff[2], boff[6];
    #pragma unroll
    for (int m = 0; m < 2; ++m) {
        int row = wm * 64 + m * 32 + l31;
        aoff[m] = row * 64 + ((hi ^ (row & 3)) << 4);
    }
    #pragma unroll
    for (int n = 0; n < 6; ++n) {
        int col = wn * 192 + n * 32 + l31;
        boff[n] = col * 64 + ((hi ^ (col & 3)) << 4);
    }

    f32x16 acc[2][6];
    #pragma unroll
    for (int m = 0; m < 2; ++m)
        #pragma unroll
        for (int n = 0; n < 6; ++n)
            #pragma unroll
            for (int r = 0; r < 16; ++r) acc[m][n][r] = 0.f;

    auto COMPUTE = [&](int cur) {
        const char* As = ldsA + cur * ATILE;
        const char* Bs = ldsB + cur * HTILE;
        #pragma unroll
        for (int kk = 0; kk < 2; ++kk) {
            bf16x8 afr[2], bfr[6];
            #pragma unroll
            for (int m = 0; m < 2; ++m)
                afr[m] = *(const bf16x8*)(As + (aoff[m] ^ (kk << 5)));
            #pragma unroll
            for (int n = 0; n < 6; ++n)
                bfr[n] = *(const bf16x8*)(Bs + (boff[n] ^ (kk << 5)));
            __builtin_amdgcn_s_setprio(1);
            #pragma unroll
            for (int m = 0; m < 2; ++m)
                #pragma unroll
                for (int n = 0; n < 6; ++n)
                    acc[m][n] = __builtin_amdgcn_mfma_f32_32x32x16_bf16(
                        afr[m], bfr[n], acc[m][n], 0, 0, 0);
            __builtin_amdgcn_s_setprio(0);
        }
    };

    // prologue: tile 0 into buffer 0 (EXACT r6 order)
    ISSUEB(0, 0);
    LOADA(0);
    STOREA(0);
    __syncthreads();

    for (int kt = 0; kt < NKT; ++kt) {
        const int cur = kt & 1;
        const bool more = (kt + 1 < NKT);
        if (more) {
            ISSUEB(kt + 1, cur ^ 1);  // DMA streams under the whole compute
            LOADA(kt + 1);
        }
        COMPUTE(cur);
        if (more) STOREA(cur ^ 1);
        __syncthreads();            // publish buffer cur^1 for next step
    }

    // epilogue: PLAIN coalesced stores of this ks-partial (no atomics).
    // 32x32 C/D layout: col=lane&31, row=(r&3)+8*(r>>2)+4*(lane>>5)
    float* Pk = P + (long)ks * PSTRIDE;
    #pragma unroll
    for (int m = 0; m < 2; ++m) {
        int rowb = row0 + wm * 64 + m * 32 + 4 * hi;
        #pragma unroll
        for (int n = 0; n < 6; ++n) {
            int col = wn * 192 + n * 32 + l31;
            #pragma unroll
            for (int r = 0; r < 16; ++r) {
                int row = rowb + (r & 3) + 8 * (r >> 2);
                Pk[(long)row * OUTD + col] = acc[m][n][r];
            }
        }
    }
}

// ---------------------------------------------------------------------------
// Kernel 3: out = sum_ks partial[ks] + negc[col]
// ---------------------------------------------------------------------------
__global__ void reduce_kernel(const float* __restrict__ P,
                              const float* __restrict__ negc,
                              float* __restrict__ out) {
    long i4 = ((long)blockIdx.x * blockDim.x + threadIdx.x) * 4;
    int col = (int)(i4 % OUTD);
    f32x4 s = *(const f32x4*)(negc + col);
    #pragma unroll
    for (int ks = 0; ks < SPLITK; ++ks)
        s += *(const f32x4*)(P + ks * PSTRIDE + i4);
    *(f32x4*)(out + i4) = s;
}

// ---------------------------------------------------------------------------
extern "C" void kernel_launch(void* const* d_in, const int* in_sizes, int n_in,
                              void* d_out, int out_size, void* d_ws,
                              size_t ws_size, hipStream_t stream) {
    const float* x = (const float*)d_in[0];
    const float* W = (const float*)d_in[1];
    const float* bp = (const float*)d_in[2];
    float* out = (float*)d_out;
    float* negc = (float*)d_ws;
    char* wsW = (char*)d_ws + WSOFF_W;
    float* wsP = (float*)((char*)d_ws + WSOFF_P);
    // ws need: ~151 MB; harness provides ~4.3 GB (0xAA fill size, r6-r10)

    hipLaunchKernelGGL(colbias_kernel, dim3(OUTD), dim3(256), 0, stream, W, bp,
                       negc);
    hipLaunchKernelGGL(cast_w_kernel, dim3(NHT_TOT), dim3(512), 0, stream, W,
                       wsW);
    hipLaunchKernelGGL(decoder_gemm, dim3((TOK / BM) * SPLITK), dim3(THREADS),
                       0, stream, x, wsW, wsP);
    hipLaunchKernelGGL(reduce_kernel, dim3((TOK * OUTD) / (256 * 4)), dim3(256),
                       0, stream, wsP, negc, out);
}